// Round 13
// baseline (174.424 us; speedup 1.0000x reference)
//
#include <hip/hip_runtime.h>

#define BB   8192   // batch (M)
#define DIN  4096   // K
#define DOUT 2048   // N

typedef unsigned short ushort_t;
typedef __attribute__((ext_vector_type(8))) short bf16x8;    // 8 bf16 (4 VGPRs)
typedef __attribute__((ext_vector_type(16))) float f32x16;   // 32x32 acc frag

// round-to-nearest-even fp32 -> bf16 bits
__device__ inline ushort_t f2bf(float f) {
    union { float f; unsigned u; } v; v.f = f;
    unsigned u = v.u;
    return (ushort_t)((u + 0x7fffu + ((u >> 16) & 1u)) >> 16);
}

// async global->LDS, 16B per lane; LDS dest = wave-uniform base (+lane*16 implicit)
#define GLOAD16(g, s)                                                        \
    __builtin_amdgcn_global_load_lds(                                        \
        (const __attribute__((address_space(1))) void*)(g),                  \
        (__attribute__((address_space(3))) void*)(s), 16, 0, 0)

#define FENCE()  asm volatile("" ::: "memory")
#define BAR()    do { FENCE(); __builtin_amdgcn_s_barrier(); FENCE(); } while (0)
#define VMCNT(n) asm volatile("s_waitcnt vmcnt(" #n ")" ::: "memory")
#define LGKM(n)  asm volatile("s_waitcnt lgkmcnt(" #n ")" ::: "memory")
#define SCHB()   __builtin_amdgcn_sched_barrier(0)

// ---------------- pre-pass 1: inputs fp32 -> bf16 ----------------
struct __align__(8) us4 { ushort_t x, y, z, w; };

__global__ __launch_bounds__(256) void convA(const float4* __restrict__ in,
                                             us4* __restrict__ out, int n4) {
    int i = blockIdx.x * blockDim.x + threadIdx.x;
    int stride = gridDim.x * blockDim.x;
    for (; i < n4; i += stride) {
        float4 v = in[i];
        us4 o;
        o.x = f2bf(v.x); o.y = f2bf(v.y); o.z = f2bf(v.z); o.w = f2bf(v.w);
        out[i] = o;
    }
}

// ---------------- pre-pass 2: WT[n][k] = bf16(kernel[k][n]*map[k][n]) ----------------
__global__ __launch_bounds__(256) void maskT(const float* __restrict__ Kn,
                                             const float* __restrict__ Mp,
                                             ushort_t* __restrict__ WT) {
    __shared__ ushort_t t[32][33];
    const int n0 = blockIdx.x * 32;
    const int k0 = blockIdx.y * 32;
    const int tx = threadIdx.x, ty = threadIdx.y;
    #pragma unroll
    for (int i = ty; i < 32; i += 8) {
        size_t idx = (size_t)(k0 + i) * DOUT + (n0 + tx);
        t[i][tx] = f2bf(Kn[idx] * Mp[idx]);
    }
    __syncthreads();
    #pragma unroll
    for (int i = ty; i < 32; i += 8) {
        WT[(size_t)(n0 + i) * DIN + (k0 + tx)] = t[tx][i];
    }
}

// ------- main GEMM: 256x256 tile, BK=64, 4 waves x 128x128, 32x32x16 MFMA -------
// R12 diagnosis: at 8 waves x 128x64 + 16x16 MFMA, LDS traffic (2304cy reads +
// 512cy DMA writes per tile per CU) exceeds the matrix-pipe floor -> 47% cap.
// Fix the RATIO: 32x32x16 (2x FLOP per b128 read) + 128x128 wave tiles
// (reads/CU-tile 192->128 b128 = 1536cy < 2048cy matrix). 1 wave/SIMD; hiding
// is per-wave software pipeline: 2 frag sets, RD(ks+1) -> LGKM(8) -> MFMA(ks).
// One vmcnt(0)+barrier per K-tile; staging leash ~ full tile (~2000cy).
// LDS layout/staging/swizzle identical to R12 (0 conflicts proven):
// buf d: A half h at d*65536+h*16384 ([128 rows][64 k] bf16, 128B rows);
//        B half h at +32768. byte_col ^= (row&7)<<4 both sides.
// Frag maps: A/B operand row=lane&31, k=(lane>>5)*8+e (analogy of validated
// 16x16 map); C/D col=lane&31, row=(reg&3)+8*(reg>>2)+4*(lane>>5) [m74/m101].
__global__ __launch_bounds__(256, 1) void gemm4(const ushort_t* __restrict__ A,   // [M][K]
                                                const ushort_t* __restrict__ BT,  // [N][K]
                                                const float* __restrict__ bias,   // [N]
                                                float* __restrict__ C) {          // [M][N]
    constexpr int K = DIN, N = DOUT;
    constexpr int NT = K / 64;           // 64 K-tiles
    extern __shared__ char sb[];         // 128 KiB

    const int tid  = threadIdx.x;
    const int lane = tid & 63;
    const int w    = tid >> 6;           // wave 0..3
    const int wr   = w >> 1;             // 0..1  (M half: rows wr*128..+127)
    const int wc   = w & 1;              // 0..1  (N half: cols wc*128..+127)
    const int l31  = lane & 31;
    const int hi   = lane >> 5;

    // bijective XCD swizzle: 256 blocks, 256 % 8 == 0
    const int orig = blockIdx.y * 8 + blockIdx.x;
    const int swz  = (orig & 7) * 32 + (orig >> 3);
    const int n0   = (swz & 7) * 256;    // N tile
    const int m0   = (swz >> 3) * 256;   // M tile

    // ---- staging: chunk (h,c) = rows c*8..c*8+7 of half h; lane l -> row
    // c*8+(l>>3), LDS 16B slot (l&7); global col16 = (l&7)^(l>>3) (inv swizzle)
    const int srow = lane >> 3;
    const int scol = ((lane & 7) ^ srow) * 8;
    const ushort_t* Ag = A  + (size_t)(m0 + srow) * K + scol;
    const ushort_t* Bg = BT + (size_t)(n0 + srow) * K + scol;

    auto stgA = [&](int buf, int kt, int h, int c) {
        GLOAD16(Ag + (size_t)(h * 128 + c * 8) * K + kt * 64,
                sb + buf * 65536 + h * 16384 + c * 1024);
    };
    auto stgB = [&](int buf, int kt, int h, int c) {
        GLOAD16(Bg + (size_t)(h * 128 + c * 8) * K + kt * 64,
                sb + buf * 65536 + 32768 + h * 16384 + c * 1024);
    };
#define STAGE_TILE(BUF, KT)                                                    \
    do {                                                                       \
        stgA(BUF, KT, 0, w);      stgA(BUF, KT, 1, w);                         \
        stgB(BUF, KT, 0, w);      stgB(BUF, KT, 1, w);                         \
        stgA(BUF, KT, 0, 4 + w);  stgA(BUF, KT, 1, 4 + w);                     \
        stgB(BUF, KT, 0, 4 + w);  stgB(BUF, KT, 1, 4 + w);                     \
        stgA(BUF, KT, 0, 8 + w);  stgA(BUF, KT, 1, 8 + w);                     \
        stgB(BUF, KT, 0, 8 + w);  stgB(BUF, KT, 1, 8 + w);                     \
        stgA(BUF, KT, 0, 12 + w); stgA(BUF, KT, 1, 12 + w);                    \
        stgB(BUF, KT, 0, 12 + w); stgB(BUF, KT, 1, 12 + w);                    \
    } while (0)

    // ---- fragment ds_read: row = frag*32 + l31 -> row&7 = lane&7 ----
    const int fxor = (lane & 7) << 4;    // swizzle XOR on byte column

#define RD(AD, BD, KS)                                                         \
    _Pragma("unroll") for (int f = 0; f < 4; ++f) {                            \
        AD[f] = *(const bf16x8*)(Ab_ + f * 4096 + l31 * 128 +                  \
                                 (((((KS) << 5) | (hi << 4))) ^ fxor));        \
        BD[f] = *(const bf16x8*)(Bb_ + f * 4096 + l31 * 128 +                  \
                                 (((((KS) << 5) | (hi << 4))) ^ fxor));        \
    }
#define MCL(AS, BS)                                                            \
    _Pragma("unroll") for (int fm = 0; fm < 4; ++fm)                           \
        _Pragma("unroll") for (int fn = 0; fn < 4; ++fn)                       \
            acc[fm][fn] = __builtin_amdgcn_mfma_f32_32x32x16_bf16(             \
                AS[fm], BS[fn], acc[fm][fn], 0, 0, 0);

    f32x16 acc[4][4] = {};   // 4 m-frags x 4 n-frags of 32x32

    // ---- prologue: tile 0 -> buf 0 ----
    STAGE_TILE(0, 0);
    VMCNT(0);
    BAR();

    int cur = 0;
    for (int t = 0; t < NT; ++t) {
        const char* Ab_ = sb + cur * 65536 + wr * 16384;
        const char* Bb_ = sb + cur * 65536 + 32768 + wc * 16384;
        const bool pf = (t + 1 < NT);

        bf16x8 a0[4], b0[4], a1[4], b1[4];
        RD(a0, b0, 0);                       // ks0: 8 ds_read
        if (pf) STAGE_TILE(1 - cur, t + 1);  // 16 gload_lds, leash = full tile
        RD(a1, b1, 1);                       // ks1 in flight under ks0 MFMA
        LGKM(8); SCHB();                     // ks0 landed
        MCL(a0, b0);
        RD(a0, b0, 2);                       // reuse set0 (WAR cleared at issue)
        LGKM(8); SCHB();                     // ks1 landed
        MCL(a1, b1);
        RD(a1, b1, 3);
        LGKM(8); SCHB();                     // ks2 landed
        MCL(a0, b0);
        LGKM(0); SCHB();                     // ks3 landed
        MCL(a1, b1);
        VMCNT(0);                            // staging issued ~2000cy ago
        BAR();
        cur ^= 1;
    }
#undef MCL
#undef RD
#undef STAGE_TILE

    // ---- epilogue: C/D col=lane&31, row=(reg&3)+8*(reg>>2)+4*hi; fused bias ----
    #pragma unroll
    for (int fn = 0; fn < 4; ++fn) {
        const int col = n0 + wc * 128 + fn * 32 + l31;
        const float bv = bias[col];
        #pragma unroll
        for (int fm = 0; fm < 4; ++fm) {
            const int r0 = m0 + wr * 128 + fm * 32 + 4 * hi;
            #pragma unroll
            for (int reg = 0; reg < 16; ++reg) {
                const int row = r0 + (reg & 3) + 8 * (reg >> 2);
                C[(size_t)row * N + col] = acc[fm][fn][reg] + bv;
            }
        }
    }
}

// ---------------- fallback (ws too small): fp32 LDS-tiled GEMM ----------------
__global__ __launch_bounds__(1024) void gemm_fb(const float* __restrict__ A,
                                                const float* __restrict__ Kn,
                                                const float* __restrict__ Mp,
                                                const float* __restrict__ bias,
                                                float* __restrict__ C) {
    __shared__ float As[32][33];
    __shared__ float Bs[32][33];
    const int tx = threadIdx.x, ty = threadIdx.y;
    const int row = blockIdx.y * 32 + ty;
    const int col = blockIdx.x * 32 + tx;
    float acc = 0.f;
    for (int kt = 0; kt < DIN; kt += 32) {
        As[ty][tx] = A[(size_t)row * DIN + kt + tx];
        size_t bidx = (size_t)(kt + ty) * DOUT + col;
        Bs[ty][tx] = Kn[bidx] * Mp[bidx];
        __syncthreads();
        #pragma unroll
        for (int kk = 0; kk < 32; ++kk)
            acc += As[ty][kk] * Bs[kk][tx];
        __syncthreads();
    }
    C[(size_t)row * DOUT + col] = acc + bias[col];
}

extern "C" void kernel_launch(void* const* d_in, const int* in_sizes, int n_in,
                              void* d_out, int out_size, void* d_ws, size_t ws_size,
                              hipStream_t stream) {
    const float* inputs = (const float*)d_in[0];   // [8192,4096]
    const float* kernel = (const float*)d_in[1];   // [4096,2048]
    const float* bias   = (const float*)d_in[2];   // [2048]
    const float* map    = (const float*)d_in[3];   // [4096,2048]
    float* out = (float*)d_out;                    // [8192,2048]

    const size_t abytes = (size_t)BB * DIN * sizeof(ushort_t);   // 64 MiB
    const size_t wbytes = (size_t)DIN * DOUT * sizeof(ushort_t); // 16 MiB

    if (ws_size >= abytes + wbytes) {
        ushort_t* Abf = (ushort_t*)d_ws;
        ushort_t* WT  = (ushort_t*)((char*)d_ws + abytes);

        static bool attr_set = false;
        if (!attr_set) {
            hipFuncSetAttribute((const void*)gemm4,
                                hipFuncAttributeMaxDynamicSharedMemorySize, 131072);
            attr_set = true;
        }

        convA<<<2048, 256, 0, stream>>>((const float4*)inputs, (us4*)Abf,
                                        (int)((size_t)BB * DIN / 4));
        maskT<<<dim3(DOUT / 32, DIN / 32), dim3(32, 8), 0, stream>>>(kernel, map, WT);
        gemm4<<<dim3(DOUT / 256, BB / 256), 256, 131072, stream>>>(Abf, WT, bias, out);
    } else {
        gemm_fb<<<dim3(DOUT / 32, BB / 32), dim3(32, 32), 0, stream>>>(inputs, kernel, map,
                                                                       bias, out);
    }
}